// Round 1
// baseline (1193.452 us; speedup 1.0000x reference)
//
#include <hip/hip_runtime.h>
#include <stdint.h>

#define D 256

typedef __attribute__((ext_vector_type(8))) short short8;
typedef __attribute__((ext_vector_type(4))) float floatx4;

__device__ __forceinline__ ushort f2bf(float f) {
    union { float f; uint32_t u; } v; v.f = f;
    uint32_t u = v.u;
    u += 0x7fffu + ((u >> 16) & 1u);   // RNE
    return (ushort)(u >> 16);
}
__device__ __forceinline__ float bf2f(ushort h) {
    union { uint32_t u; float f; } v; v.u = ((uint32_t)h) << 16;
    return v.f;
}

// ---------------- CSR build ----------------
__global__ void k_zero(int* deg, int n) {
    int i = blockIdx.x * blockDim.x + threadIdx.x;
    if (i < n) deg[i] = 0;
}

__global__ void k_hist(const int* __restrict__ erows, int* __restrict__ deg, int E) {
    int e = blockIdx.x * blockDim.x + threadIdx.x;
    if (e < E) atomicAdd(&deg[erows[e]], 1);
}

// chunk = 256 nodes
__global__ void k_scan1(const int* __restrict__ deg, int* __restrict__ part, int n, int nch) {
    int c = blockIdx.x * blockDim.x + threadIdx.x;
    if (c >= nch) return;
    int beg = c * 256, end = min(beg + 256, n);
    int s = 0;
    for (int i = beg; i < end; ++i) s += deg[i];
    part[c] = s;
}

__global__ void k_scan2(int* part, int nch) {
    __shared__ int s[512];
    int t = threadIdx.x;
    int v = (t < nch) ? part[t] : 0;
    s[t] = v;
    __syncthreads();
    for (int off = 1; off < 512; off <<= 1) {
        int x = (t >= off) ? s[t - off] : 0;
        __syncthreads();
        s[t] += x;
        __syncthreads();
    }
    if (t < nch) part[t] = s[t] - v;   // exclusive prefix
}

__global__ void k_scan3(const int* __restrict__ deg, const int* __restrict__ part,
                        int* __restrict__ rowp, int* __restrict__ cursor, int n, int nch) {
    int c = blockIdx.x * blockDim.x + threadIdx.x;
    if (c >= nch) return;
    int beg = c * 256, end = min(beg + 256, n);
    int run = part[c];
    for (int i = beg; i < end; ++i) {
        rowp[i] = run;
        cursor[i] = run;
        run += deg[i];
    }
    if (end == n) rowp[n] = run;
}

__global__ void k_scatter(const int* __restrict__ erows, const int* __restrict__ ecols,
                          const float* __restrict__ evals, int* __restrict__ cursor,
                          uint2* __restrict__ csr, int E) {
    int e = blockIdx.x * blockDim.x + threadIdx.x;
    if (e >= E) return;
    int r = erows[e];
    int p = atomicAdd(&cursor[r], 1);
    csr[p] = make_uint2((unsigned)ecols[e], __float_as_uint(evals[e]));
}

// ---------------- conversions ----------------
__global__ void k_cvt_ego(const float4* __restrict__ ego, ushort4* __restrict__ ego_bf, int n4) {
    int i = blockIdx.x * blockDim.x + threadIdx.x;
    if (i >= n4) return;
    float4 f = ego[i];
    ushort4 u;
    u.x = f2bf(f.x); u.y = f2bf(f.y); u.z = f2bf(f.z); u.w = f2bf(f.w);
    ego_bf[i] = u;
}

__global__ void k_cvt_w(const float4* __restrict__ W1, const float4* __restrict__ W2,
                        ushort4* __restrict__ W1b, ushort4* __restrict__ W2b) {
    int i = blockIdx.x * blockDim.x + threadIdx.x;   // 2 * 16384 threads
    const float4* src = (i < 16384) ? W1 : W2;
    ushort4* dst = (i < 16384) ? W1b : W2b;
    int j = i & 16383;
    float4 f = src[j];
    ushort4 u;
    u.x = f2bf(f.x); u.y = f2bf(f.y); u.z = f2bf(f.z); u.w = f2bf(f.w);
    dst[j] = u;
}

// ---------------- SpMM + bi-interaction inputs ----------------
// one wave (64 lanes) per node; lane owns 4 consecutive features
__global__ void k_spmm(const float* __restrict__ ego, const ushort* __restrict__ ego_bf,
                       const int* __restrict__ rowp, const uint2* __restrict__ csr,
                       ushort* __restrict__ X1, ushort* __restrict__ X2, int n) {
    int gtid = blockIdx.x * blockDim.x + threadIdx.x;
    int node = gtid >> 6;
    int lane = gtid & 63;
    if (node >= n) return;
    int beg = rowp[node], end = rowp[node + 1];
    int d0 = lane * 4;
    float a0 = 0.f, a1 = 0.f, a2 = 0.f, a3 = 0.f;
    for (int e = beg; e < end; ++e) {
        uint2 cv = csr[e];
        float v = __uint_as_float(cv.y);
        const ushort4 u = *(const ushort4*)(ego_bf + (size_t)cv.x * D + d0);
        a0 += v * bf2f(u.x);
        a1 += v * bf2f(u.y);
        a2 += v * bf2f(u.z);
        a3 += v * bf2f(u.w);
    }
    float4 e4 = *(const float4*)(ego + (size_t)node * D + d0);
    ushort4 o1, o2;
    o1.x = f2bf(e4.x + a0); o2.x = f2bf(e4.x * a0);
    o1.y = f2bf(e4.y + a1); o2.y = f2bf(e4.y * a1);
    o1.z = f2bf(e4.z + a2); o2.z = f2bf(e4.z * a2);
    o1.w = f2bf(e4.w + a3); o2.w = f2bf(e4.w * a3);
    *(ushort4*)(X1 + (size_t)node * D + d0) = o1;
    *(ushort4*)(X2 + (size_t)node * D + d0) = o2;
}

// ---------------- fused dual GEMM + epilogue ----------------
// block = 256 threads (4 waves); block tile = 64 rows x 256 cols; wave tile 64x64
__global__ __launch_bounds__(256) void k_gemm(
        const ushort* __restrict__ X1, const ushort* __restrict__ X2,
        const ushort* __restrict__ W1b, const ushort* __restrict__ W2b,
        const float* __restrict__ b1, const float* __restrict__ b2,
        float* __restrict__ out, int n) {
    int lane = threadIdx.x & 63;
    int w = threadIdx.x >> 6;
    int l16 = lane & 15, quad = lane >> 4;
    int row0 = blockIdx.x * 64;
    int colw = w * 64;

    floatx4 acc1[4][4], acc2[4][4];
#pragma unroll
    for (int i = 0; i < 4; ++i)
#pragma unroll
        for (int j = 0; j < 4; ++j) { acc1[i][j] = (floatx4)0.f; acc2[i][j] = (floatx4)0.f; }

    // pass 1: acc1 += X1 * W1^T
    for (int kk = 0; kk < D; kk += 32) {
        short8 a[4], b[4];
#pragma unroll
        for (int mt = 0; mt < 4; ++mt)
            a[mt] = *(const short8*)(X1 + (size_t)(row0 + mt * 16 + l16) * D + kk + quad * 8);
#pragma unroll
        for (int nt = 0; nt < 4; ++nt)
            b[nt] = *(const short8*)(W1b + (size_t)(colw + nt * 16 + l16) * D + kk + quad * 8);
#pragma unroll
        for (int mt = 0; mt < 4; ++mt)
#pragma unroll
            for (int nt = 0; nt < 4; ++nt)
                acc1[mt][nt] = __builtin_amdgcn_mfma_f32_16x16x32_bf16(a[mt], b[nt], acc1[mt][nt], 0, 0, 0);
    }
    // pass 2: acc2 += X2 * W2^T
    for (int kk = 0; kk < D; kk += 32) {
        short8 a[4], b[4];
#pragma unroll
        for (int mt = 0; mt < 4; ++mt)
            a[mt] = *(const short8*)(X2 + (size_t)(row0 + mt * 16 + l16) * D + kk + quad * 8);
#pragma unroll
        for (int nt = 0; nt < 4; ++nt)
            b[nt] = *(const short8*)(W2b + (size_t)(colw + nt * 16 + l16) * D + kk + quad * 8);
#pragma unroll
        for (int mt = 0; mt < 4; ++mt)
#pragma unroll
            for (int nt = 0; nt < 4; ++nt)
                acc2[mt][nt] = __builtin_amdgcn_mfma_f32_16x16x32_bf16(a[mt], b[nt], acc2[mt][nt], 0, 0, 0);
    }

    // epilogue: out = lrelu(acc1 + b1) + lrelu(acc2 + b2)
#pragma unroll
    for (int nt = 0; nt < 4; ++nt) {
        int col = colw + nt * 16 + l16;
        float bb1 = b1[col], bb2 = b2[col];
#pragma unroll
        for (int mt = 0; mt < 4; ++mt) {
            int row = row0 + mt * 16 + quad * 4;
#pragma unroll
            for (int r = 0; r < 4; ++r) {
                if (row + r < n) {
                    float v1 = acc1[mt][nt][r] + bb1;
                    v1 = v1 > 0.f ? v1 : 0.01f * v1;
                    float v2 = acc2[mt][nt][r] + bb2;
                    v2 = v2 > 0.f ? v2 : 0.01f * v2;
                    out[(size_t)(row + r) * D + col] = v1 + v2;
                }
            }
        }
    }
}

extern "C" void kernel_launch(void* const* d_in, const int* in_sizes, int n_in,
                              void* d_out, int out_size, void* d_ws, size_t ws_size,
                              hipStream_t stream) {
    const float* ego  = (const float*)d_in[0];
    const float* evals = (const float*)d_in[1];
    const float* W1   = (const float*)d_in[2];
    const float* b1   = (const float*)d_in[3];
    const float* W2   = (const float*)d_in[4];
    const float* b2   = (const float*)d_in[5];
    const int* erows  = (const int*)d_in[6];
    const int* ecols  = (const int*)d_in[7];
    float* out = (float*)d_out;

    int n = in_sizes[0] / D;        // 100000
    int E = in_sizes[1];            // 3200000
    int npad = (n + 63) & ~63;      // 100032

    char* p = (char*)d_ws;
    auto alloc = [&](size_t bytes) {
        char* q = p;
        p += (bytes + 511) & ~(size_t)511;
        return q;
    };
    ushort* ego_bf = (ushort*)alloc((size_t)npad * D * 2);
    ushort* X1     = (ushort*)alloc((size_t)npad * D * 2);
    ushort* X2     = (ushort*)alloc((size_t)npad * D * 2);
    ushort* W1b    = (ushort*)alloc((size_t)D * D * 2);
    ushort* W2b    = (ushort*)alloc((size_t)D * D * 2);
    int* deg       = (int*)alloc((size_t)n * 4);
    int* cursor    = (int*)alloc((size_t)n * 4);
    int* rowp      = (int*)alloc((size_t)(n + 1) * 4);
    int* part      = (int*)alloc(4096);
    uint2* csr     = (uint2*)alloc((size_t)E * 8);

    int nch = (n + 255) / 256;

    k_zero<<<(n + 255) / 256, 256, 0, stream>>>(deg, n);
    k_hist<<<(E + 255) / 256, 256, 0, stream>>>(erows, deg, E);
    k_scan1<<<(nch + 255) / 256, 256, 0, stream>>>(deg, part, n, nch);
    k_scan2<<<1, 512, 0, stream>>>(part, nch);
    k_scan3<<<(nch + 255) / 256, 256, 0, stream>>>(deg, part, rowp, cursor, n, nch);
    k_scatter<<<(E + 255) / 256, 256, 0, stream>>>(erows, ecols, evals, cursor, csr, E);

    int n4 = n * (D / 4);
    k_cvt_ego<<<(n4 + 255) / 256, 256, 0, stream>>>((const float4*)ego, (ushort4*)ego_bf, n4);
    k_cvt_w<<<(32768 + 255) / 256, 256, 0, stream>>>((const float4*)W1, (const float4*)W2,
                                                     (ushort4*)W1b, (ushort4*)W2b);

    int spmm_threads = n * 64;
    k_spmm<<<(spmm_threads + 255) / 256, 256, 0, stream>>>(ego, ego_bf, rowp, csr, X1, X2, n);

    k_gemm<<<npad / 64, 256, 0, stream>>>(X1, X2, W1b, W2b, b1, b2, out, n);
}

// Round 2
// 893.219 us; speedup vs baseline: 1.3361x; 1.3361x over previous
//
#include <hip/hip_runtime.h>
#include <hip/hip_fp16.h>
#include <stdint.h>

#define D 256
#define CHSH 13   // column-chunk shift: 8192 nodes/chunk = 4.2 MB bf16 rows ~ per-XCD L2

typedef __attribute__((ext_vector_type(8))) short short8;
typedef __attribute__((ext_vector_type(4))) float floatx4;

__device__ __forceinline__ ushort f2bf(float f) {
    union { float f; uint32_t u; } v; v.f = f;
    uint32_t u = v.u;
    u += 0x7fffu + ((u >> 16) & 1u);   // RNE
    return (ushort)(u >> 16);
}
__device__ __forceinline__ float bf2f(ushort h) {
    union { uint32_t u; float f; } v; v.u = ((uint32_t)h) << 16;
    return v.f;
}

// ---------------- bucketed CSR build ----------------
// bucket id = row*NCH + (col>>CHSH); buckets of a row are contiguous, so the
// row's edge range is [bp_excl[row*NCH], bp_excl[(row+1)*NCH]) and edges come
// out ordered by column chunk -> L2-resident gather window in spmm.

__global__ void k_hist(const int* __restrict__ er, const int* __restrict__ ec,
                       int* __restrict__ bp, int E, int NCH) {
    int e = blockIdx.x * 256 + threadIdx.x;
    if (e >= E) return;
    atomicAdd(&bp[er[e] * NCH + (ec[e] >> CHSH)], 1);
}

// block b sums bp[b*1024 .. b*1024+1023] -> part[b]
__global__ void k_red(const int* __restrict__ bp, int* __restrict__ part, int nb) {
    __shared__ int s[256];
    int t = threadIdx.x;
    int base = blockIdx.x * 1024 + t * 4;
    int v = 0;
#pragma unroll
    for (int j = 0; j < 4; ++j) if (base + j < nb) v += bp[base + j];
    s[t] = v; __syncthreads();
    for (int off = 128; off; off >>= 1) {
        if (t < off) s[t] += s[t + off];
        __syncthreads();
    }
    if (t == 0) part[blockIdx.x] = s[0];
}

// exclusive scan of part[0..np), np <= 2048, one block of 1024
__global__ __launch_bounds__(1024) void k_scanpart(int* __restrict__ part, int np) {
    __shared__ int s[1024];
    int t = threadIdx.x;
    int p0 = (2 * t < np) ? part[2 * t] : 0;
    int p1 = (2 * t + 1 < np) ? part[2 * t + 1] : 0;
    int v = p0 + p1;
    s[t] = v; __syncthreads();
    for (int off = 1; off < 1024; off <<= 1) {
        int x = (t >= off) ? s[t - off] : 0;
        __syncthreads();
        s[t] += x;
        __syncthreads();
    }
    int excl = s[t] - v;
    if (2 * t < np) part[2 * t] = excl;
    if (2 * t + 1 < np) part[2 * t + 1] = excl + p0;
}

// in-place exclusive scan of bp within each 1024 chunk, + part[b]
__global__ void k_scan3(int* __restrict__ bp, const int* __restrict__ part, int nb) {
    __shared__ int s[256];
    int t = threadIdx.x;
    int base = blockIdx.x * 1024 + t * 4;
    int d0 = 0, d1 = 0, d2 = 0, d3 = 0;
    if (base     < nb) d0 = bp[base];
    if (base + 1 < nb) d1 = bp[base + 1];
    if (base + 2 < nb) d2 = bp[base + 2];
    if (base + 3 < nb) d3 = bp[base + 3];
    int sum = d0 + d1 + d2 + d3;
    s[t] = sum; __syncthreads();
    for (int off = 1; off < 256; off <<= 1) {
        int x = (t >= off) ? s[t - off] : 0;
        __syncthreads();
        s[t] += x;
        __syncthreads();
    }
    int run = part[blockIdx.x] + s[t] - sum;   // exclusive prefix
    if (base     < nb) bp[base]     = run; run += d0;
    if (base + 1 < nb) bp[base + 1] = run; run += d1;
    if (base + 2 < nb) bp[base + 2] = run; run += d2;
    if (base + 3 < nb) bp[base + 3] = run;
}

// scatter, bumping bp in place: afterwards bp[i] = end of bucket i
__global__ void k_scatter(const int* __restrict__ er, const int* __restrict__ ec,
                          const float* __restrict__ ev, int* __restrict__ bp,
                          uint32_t* __restrict__ csr, int E, int NCH) {
    int e = blockIdx.x * 256 + threadIdx.x;
    if (e >= E) return;
    int col = ec[e];
    int p = atomicAdd(&bp[er[e] * NCH + (col >> CHSH)], 1);
    ushort hb = __half_as_ushort(__float2half_rn(ev[e]));   // val in [0,1/32): sign bit free
    csr[p] = ((uint32_t)col << 15) | (uint32_t)hb;
}

// ---------------- conversions (ego + W fused) ----------------
__global__ void k_cvt(const float4* __restrict__ ego, ushort4* __restrict__ ego_bf,
                      const float4* __restrict__ W1, const float4* __restrict__ W2,
                      ushort4* __restrict__ W1b, ushort4* __restrict__ W2b, int n4) {
    int i = blockIdx.x * 256 + threadIdx.x;
    const float4* src;
    ushort4* dst;
    if (i < n4) { src = ego + i; dst = ego_bf + i; }
    else {
        int j = i - n4;
        if (j >= 32768) return;
        int k = j & 16383;
        src = ((j < 16384) ? W1 : W2) + k;
        dst = ((j < 16384) ? W1b : W2b) + k;
    }
    float4 f = *src;
    ushort4 u;
    u.x = f2bf(f.x); u.y = f2bf(f.y); u.z = f2bf(f.z); u.w = f2bf(f.w);
    *dst = u;
}

// ---------------- SpMM + bi-interaction inputs ----------------
// one wave per node; lane owns 4 consecutive features; edge loop unrolled x8
__global__ void k_spmm(const ushort* __restrict__ ego_bf, const int* __restrict__ bp,
                       const uint32_t* __restrict__ csr,
                       ushort* __restrict__ X1, ushort* __restrict__ X2, int n, int NCH) {
    int gtid = blockIdx.x * 256 + threadIdx.x;
    int node = gtid >> 6;
    int lane = gtid & 63;
    if (node >= n) return;
    // post-scatter bp[i] = end of bucket i, so row range is:
    int beg = (node == 0) ? 0 : bp[node * NCH - 1];
    int end = bp[(node + 1) * NCH - 1];
    int d0 = lane * 4;
    float a0 = 0.f, a1 = 0.f, a2 = 0.f, a3 = 0.f;
    int e = beg;
    for (; e + 8 <= end; e += 8) {
        uint32_t w[8];
#pragma unroll
        for (int j = 0; j < 8; ++j) w[j] = csr[e + j];
        ushort4 u[8];
#pragma unroll
        for (int j = 0; j < 8; ++j)
            u[j] = *(const ushort4*)(ego_bf + (size_t)(w[j] >> 15) * D + d0);
#pragma unroll
        for (int j = 0; j < 8; ++j) {
            float v = __half2float(__ushort_as_half((ushort)(w[j] & 0x7fff)));
            a0 += v * bf2f(u[j].x);
            a1 += v * bf2f(u[j].y);
            a2 += v * bf2f(u[j].z);
            a3 += v * bf2f(u[j].w);
        }
    }
    for (; e < end; ++e) {
        uint32_t w = csr[e];
        float v = __half2float(__ushort_as_half((ushort)(w & 0x7fff)));
        ushort4 u = *(const ushort4*)(ego_bf + (size_t)(w >> 15) * D + d0);
        a0 += v * bf2f(u.x);
        a1 += v * bf2f(u.y);
        a2 += v * bf2f(u.z);
        a3 += v * bf2f(u.w);
    }
    ushort4 eg = *(const ushort4*)(ego_bf + (size_t)node * D + d0);
    float e0 = bf2f(eg.x), e1 = bf2f(eg.y), e2 = bf2f(eg.z), e3 = bf2f(eg.w);
    ushort4 o1, o2;
    o1.x = f2bf(e0 + a0); o2.x = f2bf(e0 * a0);
    o1.y = f2bf(e1 + a1); o2.y = f2bf(e1 * a1);
    o1.z = f2bf(e2 + a2); o2.z = f2bf(e2 * a2);
    o1.w = f2bf(e3 + a3); o2.w = f2bf(e3 * a3);
    *(ushort4*)(X1 + (size_t)node * D + d0) = o1;
    *(ushort4*)(X2 + (size_t)node * D + d0) = o2;
}

// ---------------- fused dual GEMM + epilogue ----------------
__global__ __launch_bounds__(256) void k_gemm(
        const ushort* __restrict__ X1, const ushort* __restrict__ X2,
        const ushort* __restrict__ W1b, const ushort* __restrict__ W2b,
        const float* __restrict__ b1, const float* __restrict__ b2,
        float* __restrict__ out, int n) {
    int lane = threadIdx.x & 63;
    int w = threadIdx.x >> 6;
    int l16 = lane & 15, quad = lane >> 4;
    int row0 = blockIdx.x * 64;
    int colw = w * 64;

    floatx4 acc1[4][4], acc2[4][4];
#pragma unroll
    for (int i = 0; i < 4; ++i)
#pragma unroll
        for (int j = 0; j < 4; ++j) { acc1[i][j] = (floatx4)0.f; acc2[i][j] = (floatx4)0.f; }

    for (int kk = 0; kk < D; kk += 32) {
        short8 a[4], b[4];
#pragma unroll
        for (int mt = 0; mt < 4; ++mt)
            a[mt] = *(const short8*)(X1 + (size_t)(row0 + mt * 16 + l16) * D + kk + quad * 8);
#pragma unroll
        for (int nt = 0; nt < 4; ++nt)
            b[nt] = *(const short8*)(W1b + (size_t)(colw + nt * 16 + l16) * D + kk + quad * 8);
#pragma unroll
        for (int mt = 0; mt < 4; ++mt)
#pragma unroll
            for (int nt = 0; nt < 4; ++nt)
                acc1[mt][nt] = __builtin_amdgcn_mfma_f32_16x16x32_bf16(a[mt], b[nt], acc1[mt][nt], 0, 0, 0);
    }
    for (int kk = 0; kk < D; kk += 32) {
        short8 a[4], b[4];
#pragma unroll
        for (int mt = 0; mt < 4; ++mt)
            a[mt] = *(const short8*)(X2 + (size_t)(row0 + mt * 16 + l16) * D + kk + quad * 8);
#pragma unroll
        for (int nt = 0; nt < 4; ++nt)
            b[nt] = *(const short8*)(W2b + (size_t)(colw + nt * 16 + l16) * D + kk + quad * 8);
#pragma unroll
        for (int mt = 0; mt < 4; ++mt)
#pragma unroll
            for (int nt = 0; nt < 4; ++nt)
                acc2[mt][nt] = __builtin_amdgcn_mfma_f32_16x16x32_bf16(a[mt], b[nt], acc2[mt][nt], 0, 0, 0);
    }

#pragma unroll
    for (int nt = 0; nt < 4; ++nt) {
        int col = colw + nt * 16 + l16;
        float bb1 = b1[col], bb2 = b2[col];
#pragma unroll
        for (int mt = 0; mt < 4; ++mt) {
            int row = row0 + mt * 16 + quad * 4;
#pragma unroll
            for (int r = 0; r < 4; ++r) {
                if (row + r < n) {
                    float v1 = acc1[mt][nt][r] + bb1;
                    v1 = v1 > 0.f ? v1 : 0.01f * v1;
                    float v2 = acc2[mt][nt][r] + bb2;
                    v2 = v2 > 0.f ? v2 : 0.01f * v2;
                    out[(size_t)(row + r) * D + col] = v1 + v2;
                }
            }
        }
    }
}

extern "C" void kernel_launch(void* const* d_in, const int* in_sizes, int n_in,
                              void* d_out, int out_size, void* d_ws, size_t ws_size,
                              hipStream_t stream) {
    const float* ego   = (const float*)d_in[0];
    const float* evals = (const float*)d_in[1];
    const float* W1    = (const float*)d_in[2];
    const float* b1    = (const float*)d_in[3];
    const float* W2    = (const float*)d_in[4];
    const float* b2    = (const float*)d_in[5];
    const int* erows   = (const int*)d_in[6];
    const int* ecols   = (const int*)d_in[7];
    float* out = (float*)d_out;

    int n = in_sizes[0] / D;          // 100000
    int E = in_sizes[1];              // 3200000
    int npad = (n + 63) & ~63;        // 100032
    int NCH = (n + (1 << CHSH) - 1) >> CHSH;   // 13
    int nb = n * NCH;                 // 1.3M buckets
    int np = (nb + 1023) / 1024;      // partial count (<=2048)

    char* p = (char*)d_ws;
    auto alloc = [&](size_t bytes) {
        char* q = p;
        p += (bytes + 511) & ~(size_t)511;
        return q;
    };
    ushort* ego_bf = (ushort*)alloc((size_t)n * D * 2);      // 51.2 MB
    ushort* X1     = (ushort*)alloc((size_t)npad * D * 2);   // 51.2 MB
    ushort* X2     = (ushort*)alloc((size_t)npad * D * 2);   // 51.2 MB
    ushort* W1b    = (ushort*)alloc((size_t)D * D * 2);
    ushort* W2b    = (ushort*)alloc((size_t)D * D * 2);
    int* bp        = (int*)alloc((size_t)nb * 4);            // 5.2 MB
    int* part      = (int*)alloc((size_t)np * 4);
    uint32_t* csr  = (uint32_t*)alloc((size_t)E * 4);        // 12.8 MB

    hipMemsetAsync(bp, 0, (size_t)nb * 4, stream);
    k_hist<<<(E + 255) / 256, 256, 0, stream>>>(erows, ecols, bp, E, NCH);
    k_red<<<np, 256, 0, stream>>>(bp, part, nb);
    k_scanpart<<<1, 1024, 0, stream>>>(part, np);
    k_scan3<<<np, 256, 0, stream>>>(bp, part, nb);
    k_scatter<<<(E + 255) / 256, 256, 0, stream>>>(erows, ecols, evals, bp, csr, E, NCH);

    int n4 = n * (D / 4);
    k_cvt<<<(n4 + 32768 + 255) / 256, 256, 0, stream>>>((const float4*)ego, (ushort4*)ego_bf,
                                                        (const float4*)W1, (const float4*)W2,
                                                        (ushort4*)W1b, (ushort4*)W2b, n4);

    k_spmm<<<(n * 64 + 255) / 256, 256, 0, stream>>>(ego_bf, bp, csr, X1, X2, n, NCH);

    k_gemm<<<npad / 64, 256, 0, stream>>>(X1, X2, W1b, W2b, b1, b2, out, n);
}